// Round 9
// baseline (170.033 us; speedup 1.0000x reference)
//
#include <hip/hip_runtime.h>
#include <hip/hip_bf16.h>
#include <math.h>

#define B_  8
#define C_  256
#define CR_ 32
#define N_  4096

typedef __attribute__((ext_vector_type(8)))  short bf16x8;   // 8 bf16 = 4 VGPR
typedef __attribute__((ext_vector_type(16))) float f32x16;   // MFMA 32x32 acc
typedef __attribute__((ext_vector_type(4)))  int   int4v;

__device__ inline unsigned short f2b(float x) {
    __hip_bfloat16 h = __float2bfloat16(x);
    return __builtin_bit_cast(unsigned short, h);
}

// async 16B global->LDS (wave-uniform LDS base + lane*16; per-lane global src)
#define GLL16(gsrc, ldst) \
    __builtin_amdgcn_global_load_lds((const __attribute__((address_space(1))) void*)(gsrc), \
                                     (__attribute__((address_space(3))) void*)(ldst), 16, 0, 0)

// ---------------------------------------------------------------------------
// Kernel 0: pack weights to bf16.
//   W1[320][256]: rows 0-31 wq*log2e | 32-63 wk | 64-319 wv;  Bs1[320] fp32
//   W2[256][256]: wo
// ---------------------------------------------------------------------------
__global__ void pack_kernel(
    const float* __restrict__ wq, const float* __restrict__ bq,
    const float* __restrict__ wk, const float* __restrict__ bk,
    const float* __restrict__ wv, const float* __restrict__ bv,
    const float* __restrict__ wo,
    unsigned short* __restrict__ W1, unsigned short* __restrict__ W2,
    float* __restrict__ Bs1)
{
    const int r = blockIdx.x, t = threadIdx.x;
    const float L2E = 1.44269504088896340736f;
    if (r < 320) {
        float w;
        if (r < 32)      w = wq[r * C_ + t] * L2E;
        else if (r < 64) w = wk[(r - 32) * C_ + t];
        else             w = wv[(r - 64) * C_ + t];
        W1[r * C_ + t] = f2b(w);
        if (t == 0)
            Bs1[r] = (r < 32) ? bq[r] * L2E : ((r < 64) ? bk[r - 32] : bv[r - 64]);
    } else {
        W2[(r - 320) * C_ + t] = f2b(wo[(r - 320) * C_ + t]);
    }
}

// ---------------------------------------------------------------------------
// Kernel 1: transpose+convert  x,f fp32 [C,N] -> xT,fT bf16 [N,C].
// ---------------------------------------------------------------------------
__global__ __launch_bounds__(256) void convT_kernel(
    const float* __restrict__ x, const float* __restrict__ f,
    unsigned short* __restrict__ xT, unsigned short* __restrict__ fT)
{
    __shared__ float tile[64][65];
    const int t  = threadIdx.x;
    const int n0 = blockIdx.x * 64;
    const int c0 = blockIdx.y * 64;
    const int z  = blockIdx.z;
    const int b  = z >> 1;
    const float* src = (z & 1) ? f : x;
    unsigned short* dst = (z & 1) ? fT : xT;
    const size_t so = (size_t)b * C_ * N_;

    #pragma unroll
    for (int it = 0; it < 4; ++it) {
        const int cl = it * 16 + (t >> 4);
        *(float4*)&tile[cl][(t & 15) * 4] =
            *(const float4*)&src[so + (size_t)(c0 + cl) * N_ + n0 + (t & 15) * 4];
    }
    __syncthreads();

    const int nl = t >> 2;
    const int cg = (t & 3) * 16;
    unsigned short* drow = dst + ((size_t)b * N_ + n0 + nl) * C_ + c0 + cg;
    int4v w0, w1;
    #pragma unroll
    for (int e = 0; e < 4; ++e)
        w0[e] = (int)(((unsigned)f2b(tile[cg + 2*e][nl])) |
                      (((unsigned)f2b(tile[cg + 2*e + 1][nl])) << 16));
    #pragma unroll
    for (int e = 0; e < 4; ++e)
        w1[e] = (int)(((unsigned)f2b(tile[cg + 8 + 2*e][nl])) |
                      (((unsigned)f2b(tile[cg + 9 + 2*e][nl])) << 16));
    *(int4v*)(drow)     = w0;
    *(int4v*)(drow + 8) = w1;
}

// ---------------------------------------------------------------------------
// Shared MFMA GEMM mainloop (unchanged from R4).
// ---------------------------------------------------------------------------
__device__ __forceinline__ void gemm_mainloop(
    const unsigned short* __restrict__ Asrc,
    const unsigned short* __restrict__ Bsrc,
    unsigned short (*Ab)[32 * 32], unsigned short (*Bb)[256 * 32],
    int w, int l, f32x16& acc0, f32x16& acc1)
{
    const int jl = l & 31, hi = l >> 5;
    const int fj = (jl >> 1) & 3;

#define STAGE(KK, BUF) { \
    _Pragma("unroll") \
    for (int p = 0; p < 4; ++p) { \
        const int idx = p * 256 + w * 64 + l; \
        const int row = idx >> 2, slot = idx & 3; \
        GLL16(Bsrc + (size_t)row * 256 + (KK) * 32 + (slot ^ ((row >> 1) & 3)) * 8, \
              Bb[BUF] + (size_t)(p * 256 + w * 64) * 8); \
    } \
    if (w == 0) { \
        _Pragma("unroll") \
        for (int qq = 0; qq < 2; ++qq) { \
            const int idx = qq * 64 + l; \
            const int row = idx >> 2, slot = idx & 3; \
            GLL16(Asrc + (size_t)row * 256 + (KK) * 32 + (slot ^ ((row >> 1) & 3)) * 8, \
                  Ab[BUF] + (size_t)(qq * 64) * 8); \
        } \
    } }

    STAGE(0, 0)
    __syncthreads();

    for (int kk = 0; kk < 8; ++kk) {
        const int cur = kk & 1;
        if (kk < 7) STAGE(kk + 1, cur ^ 1)

        const unsigned short* Ac = Ab[cur];
        const unsigned short* Bc = Bb[cur];
        const bf16x8 af0 = *(const bf16x8*)&Ac[jl * 32 + ((hi ^ fj) * 8)];
        const bf16x8 af1 = *(const bf16x8*)&Ac[jl * 32 + (((2 + hi) ^ fj) * 8)];
        const int r0 = w * 64 + jl, r1 = w * 64 + 32 + jl;
        const bf16x8 bf00 = *(const bf16x8*)&Bc[r0 * 32 + ((hi ^ fj) * 8)];
        const bf16x8 bf01 = *(const bf16x8*)&Bc[r0 * 32 + (((2 + hi) ^ fj) * 8)];
        const bf16x8 bf10 = *(const bf16x8*)&Bc[r1 * 32 + ((hi ^ fj) * 8)];
        const bf16x8 bf11 = *(const bf16x8*)&Bc[r1 * 32 + (((2 + hi) ^ fj) * 8)];

        acc0 = __builtin_amdgcn_mfma_f32_32x32x16_bf16(af0, bf00, acc0, 0, 0, 0);
        acc0 = __builtin_amdgcn_mfma_f32_32x32x16_bf16(af1, bf01, acc0, 0, 0, 0);
        acc1 = __builtin_amdgcn_mfma_f32_32x32x16_bf16(af0, bf10, acc1, 0, 0, 0);
        acc1 = __builtin_amdgcn_mfma_f32_32x32x16_bf16(af1, bf11, acc1, 0, 0, 0);
        __syncthreads();
    }
#undef STAGE
}

// ---------------------------------------------------------------------------
// Kernel 2: QKV projection GEMM (unchanged from R4).
// ---------------------------------------------------------------------------
__global__ __launch_bounds__(256) void qkv_gemm(
    const unsigned short* __restrict__ xT, const unsigned short* __restrict__ fT,
    const unsigned short* __restrict__ W1, const float* __restrict__ Bs1,
    unsigned short* __restrict__ qT, unsigned short* __restrict__ kT,
    unsigned short* __restrict__ v)
{
    __shared__ __align__(16) unsigned short Ab[2][32 * 32];
    __shared__ __align__(16) unsigned short Bb[2][256 * 32];

    const int t = threadIdx.x;
    const int w = t >> 6, l = t & 63;
    const int jl = l & 31, hi = l >> 5;
    const int bid = blockIdx.x;
    const int b  = bid & 7;
    const int r_ = bid >> 3;
    const int mt = r_ % 10;
    const int nt = r_ / 10;

    const unsigned short* Asrc = W1 + (size_t)mt * 32 * C_;
    const unsigned short* Bsrc = ((mt == 0) ? xT : fT) + (size_t)b * N_ * C_
                               + (size_t)nt * 256 * C_;

    f32x16 acc0 = (f32x16)0.f, acc1 = (f32x16)0.f;
    gemm_mainloop(Asrc, Bsrc, Ab, Bb, w, l, acc0, acc1);

    const int m0 = mt * 32;
    const int nb = nt * 256 + w * 64;
    if (mt <= 1) {
        unsigned short* dst = ((mt == 0) ? qT : kT) + (size_t)b * N_ * CR_;
        #pragma unroll
        for (int ns = 0; ns < 2; ++ns) {
            const f32x16& A = ns ? acc1 : acc0;
            const int n = nb + ns * 32 + jl;
            #pragma unroll
            for (int r4 = 0; r4 < 4; ++r4) {
                const float4 bi = *(const float4*)&Bs1[m0 + r4 * 8 + 4 * hi];
                const unsigned int d0 = (unsigned)f2b(A[r4*4+0] + bi.x) |
                                        ((unsigned)f2b(A[r4*4+1] + bi.y) << 16);
                const unsigned int d1 = (unsigned)f2b(A[r4*4+2] + bi.z) |
                                        ((unsigned)f2b(A[r4*4+3] + bi.w) << 16);
                *(uint2*)(dst + (size_t)n * CR_ + r4 * 8 + 4 * hi) = make_uint2(d0, d1);
            }
        }
    } else {
        unsigned short* dst = v + (size_t)b * C_ * N_;
        #pragma unroll
        for (int ns = 0; ns < 2; ++ns) {
            const f32x16& A = ns ? acc1 : acc0;
            const int n = nb + ns * 32 + jl;
            #pragma unroll
            for (int r4 = 0; r4 < 4; ++r4) {
                const float4 bi = *(const float4*)&Bs1[m0 + r4 * 8 + 4 * hi];
                #pragma unroll
                for (int e = 0; e < 4; ++e) {
                    const int c = m0 - 64 + e + 8 * r4 + 4 * hi;
                    dst[(size_t)c * N_ + n] = f2b(A[r4*4+e] + ((const float*)&bi)[e]);
                }
            }
        }
    }
}

// ---------------------------------------------------------------------------
// Kernel 3: MFMA flash attention v7 — de-synchronization round.
// Grid 256 (1 block/CU), block 512 = 8 waves = 4 ig x 2 cs; i-tile 128.
// KVBLK = 128: V dbuf 2 x 64 KB LDS (global_load_lds, 8-slot row XOR),
// ONE barrier per 128 j (32 total). Each tile = 4 independent 32-j
// sub-rounds {K-prefetch -> S(2 MFMA) -> softmax -> PV(8 MFMA)} with no
// barrier between: waves drift and pipes (matrix/trans/LDS) interleave.
// K register-pipelined direct from global (L1-resident), 1 sub-round ahead.
// Streaming softmax (bounded scores, no max tracking).
// ---------------------------------------------------------------------------
__device__ inline void softmax_tile(const f32x16& s, float& lsum,
                                    bf16x8& pf0, bf16x8& pf1)
{
    float ps = 0.f;
    int wd[8];
    #pragma unroll
    for (int r = 0; r < 16; r += 2) {
        float e0 = __builtin_amdgcn_exp2f(s[r]);
        float e1 = __builtin_amdgcn_exp2f(s[r + 1]);
        ps += e0 + e1;
        int pk;
        asm("v_cvt_pk_bf16_f32 %0, %1, %2" : "=v"(pk) : "v"(e0), "v"(e1));
        wd[r >> 1] = pk;
    }
    lsum += ps;                       // per-lane partial; merged after the loop
    asm volatile("v_permlane32_swap_b32 %0, %1" : "+v"(wd[0]), "+v"(wd[2]));
    asm volatile("v_permlane32_swap_b32 %0, %1" : "+v"(wd[1]), "+v"(wd[3]));
    asm volatile("v_permlane32_swap_b32 %0, %1" : "+v"(wd[4]), "+v"(wd[6]));
    asm volatile("v_permlane32_swap_b32 %0, %1" : "+v"(wd[5]), "+v"(wd[7]));
    union { int4v i4; bf16x8 h8; } u0, u1;
    u0.i4 = (int4v){ wd[0], wd[1], wd[2], wd[3] };   // k = j0 .. j0+15
    u1.i4 = (int4v){ wd[4], wd[5], wd[6], wd[7] };   // k = j0+16 .. j0+31
    pf0 = u0.h8; pf1 = u1.h8;
}

__global__ __launch_bounds__(512) void attn_kernel(
    const unsigned short* __restrict__ qT, const unsigned short* __restrict__ kT,
    const unsigned short* __restrict__ v, unsigned short* __restrict__ aoT)
{
    __shared__ __align__(16) unsigned short Vt[2][256 * 128];  // 2 x 64 KB

    const int t  = threadIdx.x;
    const int w  = t >> 6;
    const int l  = t & 63;
    const int jl = l & 31;
    const int hi = l >> 5;
    const int ig = w >> 1;             // 32-i subtile (0..3)
    const int cs = w & 1;              // 128-channel half

    const int bid = blockIdx.x;
    const int b   = bid & 7;           // XCD-local batch
    const int it  = bid >> 3;          // 0..31
    const int i   = it * 128 + ig * 32 + jl;

    const unsigned short* qTb = qT + (size_t)b * N_ * CR_;
    const unsigned short* kTb = kT + (size_t)b * N_ * CR_;
    const unsigned short* vb  = v  + (size_t)b * C_ * N_;

    // Q fragments (B operand: col=i, k=d)
    const bf16x8 qa0 = *(const bf16x8*)(qTb + (size_t)i * CR_ + hi * 8);
    const bf16x8 qa1 = *(const bf16x8*)(qTb + (size_t)i * CR_ + 16 + hi * 8);

    // K per-lane base: row j (=jl within 32-j sub-round), frag at hi*8
    const unsigned short* kln = kTb + (size_t)jl * CR_ + hi * 8;

    // ---- V staging (linear LDS dest + inverse-swizzled global src) ----
    // tile = 256 c-rows x 128 j (256B rows, 16 chunks); 4096 chunks,
    // 8 rounds x 512 threads; row = chunk/16 (c), slot = chunk%16.
    // slot s holds logical chunk q = s ^ (row & 7).
    const unsigned short* vsrc[8];
    int vdst[8];
    #pragma unroll
    for (int p = 0; p < 8; ++p) {
        const int idx = p * 512 + t;
        const int row = idx >> 4, slot = idx & 15;
        vsrc[p] = vb + (size_t)row * N_ + (slot ^ (row & 7)) * 8;
        vdst[p] = idx * 8;             // shorts (linear)
    }

    f32x16 acc0 = (f32x16)0.f, acc1 = (f32x16)0.f;
    f32x16 acc2 = (f32x16)0.f, acc3 = (f32x16)0.f;
    float lsa = 0.f;

    // prologue: stage V tile 0; load K sub-round 0 into registers
    #pragma unroll
    for (int p = 0; p < 8; ++p) GLL16(vsrc[p], &Vt[0][vdst[p]]);
    bf16x8 kc0 = *(const bf16x8*)(kln);
    bf16x8 kc1 = *(const bf16x8*)(kln + 16);
    __syncthreads();

    // V rows for the 4 c-tiles of this wave's 128-channel half
    int vrow[4];
    #pragma unroll
    for (int ct = 0; ct < 4; ++ct) vrow[ct] = cs * 128 + ct * 32 + jl;

    for (int jt = 0; jt < N_ / 128; ++jt) {
        const int cur = jt & 1;
        if (jt + 1 < N_ / 128) {       // prefetch next V tile into other buffer
            const size_t jn = (size_t)(jt + 1) * 128;
            #pragma unroll
            for (int p = 0; p < 8; ++p) GLL16(vsrc[p] + jn, &Vt[cur ^ 1][vdst[p]]);
        }

        #pragma unroll
        for (int sub = 0; sub < 4; ++sub) {
            // K prefetch for next sub-round (or next tile's sub 0)
            const size_t koff = (sub < 3)
                ? ((size_t)jt * 128 + (sub + 1) * 32) * CR_
                : ((jt + 1 < N_ / 128) ? (size_t)(jt + 1) * 128 * CR_ : 0);
            const bf16x8 kn0 = *(const bf16x8*)(kln + koff);
            const bf16x8 kn1 = *(const bf16x8*)(kln + koff + 16);

            // ---- S^T: A = K (row=j, k=d), B = Q (col=i, k=d) ----
            __builtin_amdgcn_s_setprio(1);
            f32x16 s = (f32x16)0.f;
            s = __builtin_amdgcn_mfma_f32_32x32x16_bf16(kc0, qa0, s, 0, 0, 0);
            s = __builtin_amdgcn_mfma_f32_32x32x16_bf16(kc1, qa1, s, 0, 0, 0);
            __builtin_amdgcn_s_setprio(0);

            bf16x8 p0, p1;
            softmax_tile(s, lsa, p0, p1);

            // ---- PV: A = V (row=c, k=j), B = P^T (col=i, k=j) ----
            // logical chunks: q0 = sub*4 + hi (k=j0..j0+15), q1 = q0 + 2
            __builtin_amdgcn_s_setprio(1);
            #pragma unroll
            for (int ct = 0; ct < 4; ++ct) {
                const int r = vrow[ct];
                const bf16x8 v0 = *(const bf16x8*)
                    &Vt[cur][r * 128 + (((sub * 4 + hi) ^ (r & 7)) * 8)];
                const bf16x8 v1 = *(const bf16x8*)
                    &Vt[cur][r * 128 + (((sub * 4 + 2 + hi) ^ (r & 7)) * 8)];
                f32x16& A = (ct == 0) ? acc0 : (ct == 1) ? acc1 : (ct == 2) ? acc2 : acc3;
                A = __builtin_amdgcn_mfma_f32_32x32x16_bf16(v0, p0, A, 0, 0, 0);
                A = __builtin_amdgcn_mfma_f32_32x32x16_bf16(v1, p1, A, 0, 0, 0);
            }
            __builtin_amdgcn_s_setprio(0);

            kc0 = kn0; kc1 = kn1;
        }

        __syncthreads();   // staged tile ready; cur buffer free for overwrite
    }

    // ---- finalize: merge lane-half partial sums, normalize, store ----
    lsa += __shfl_xor(lsa, 32);
    const float ra = 1.f / lsa;
    unsigned short* aoTb = aoT + (size_t)b * N_ * C_;
#define EPI(ACC, CT) { _Pragma("unroll") \
    for (int r4 = 0; r4 < 4; ++r4) { \
        const unsigned int d0 = (unsigned)f2b(ACC[r4*4+0] * ra) | \
                                ((unsigned)f2b(ACC[r4*4+1] * ra) << 16); \
        const unsigned int d1 = (unsigned)f2b(ACC[r4*4+2] * ra) | \
                                ((unsigned)f2b(ACC[r4*4+3] * ra) << 16); \
        *(uint2*)(aoTb + (size_t)i * C_ + cs * 128 + (CT) * 32 + r4 * 8 + 4 * hi) \
            = make_uint2(d0, d1); } }
    EPI(acc0, 0)
    EPI(acc1, 1)
    EPI(acc2, 2)
    EPI(acc3, 3)
#undef EPI
}

// ---------------------------------------------------------------------------
// Kernel 4: output projection GEMM + gated residual (unchanged from R4).
// ---------------------------------------------------------------------------
__global__ __launch_bounds__(256) void out_gemm(
    const unsigned short* __restrict__ aoT, const unsigned short* __restrict__ W2,
    const float* __restrict__ bo, const float* __restrict__ gamma,
    const float* __restrict__ x, float* __restrict__ out)
{
    __shared__ __align__(16) unsigned short Ab[2][32 * 32];
    __shared__ __align__(16) unsigned short Bb[2][256 * 32];

    const int t = threadIdx.x;
    const int w = t >> 6, l = t & 63;
    const int jl = l & 31, hi = l >> 5;
    const int bid = blockIdx.x;
    const int b  = bid & 7;
    const int r_ = bid >> 3;
    const int mt = r_ & 7;
    const int nt = r_ >> 3;

    const unsigned short* Asrc = W2 + (size_t)mt * 32 * C_;
    const unsigned short* Bsrc = aoT + (size_t)b * N_ * C_ + (size_t)nt * 256 * C_;

    f32x16 acc0 = (f32x16)0.f, acc1 = (f32x16)0.f;
    gemm_mainloop(Asrc, Bsrc, Ab, Bb, w, l, acc0, acc1);

    const float gm = gamma[0];
    const int m0 = mt * 32;
    const int nb = nt * 256 + w * 64;
    #pragma unroll
    for (int ns = 0; ns < 2; ++ns) {
        const f32x16& A = ns ? acc1 : acc0;
        const int n = nb + ns * 32 + jl;
        #pragma unroll
        for (int r4 = 0; r4 < 4; ++r4) {
            const float4 bi = *(const float4*)&bo[m0 + r4 * 8 + 4 * hi];
            #pragma unroll
            for (int e = 0; e < 4; ++e) {
                const int c = m0 + e + 8 * r4 + 4 * hi;
                const size_t o = ((size_t)b * C_ + c) * N_ + n;
                out[o] = fmaf(gm, A[r4*4+e] + ((const float*)&bi)[e], x[o]);
            }
        }
    }
}

// ---------------------------------------------------------------------------
extern "C" void kernel_launch(void* const* d_in, const int* in_sizes, int n_in,
                              void* d_out, int out_size, void* d_ws, size_t ws_size,
                              hipStream_t stream)
{
    const float* x     = (const float*)d_in[0];
    const float* f     = (const float*)d_in[1];
    const float* wq    = (const float*)d_in[2];
    const float* bq    = (const float*)d_in[3];
    const float* wk    = (const float*)d_in[4];
    const float* bk    = (const float*)d_in[5];
    const float* wv    = (const float*)d_in[6];
    const float* bv    = (const float*)d_in[7];
    const float* wo    = (const float*)d_in[8];
    const float* bo    = (const float*)d_in[9];
    const float* gamma = (const float*)d_in[10];
    float* out = (float*)d_out;

    float* Bs1 = (float*)d_ws;
    unsigned short* W1 = (unsigned short*)(Bs1 + 320);
    unsigned short* W2 = W1 + 320 * C_;
    unsigned short* xT = W2 + 256 * C_;
    unsigned short* fT = xT + (size_t)B_ * N_ * C_;
    unsigned short* qT = fT + (size_t)B_ * N_ * C_;
    unsigned short* kT = qT + (size_t)B_ * N_ * CR_;
    unsigned short* vv = kT + (size_t)B_ * N_ * CR_;
    unsigned short* aoT = vv + (size_t)B_ * C_ * N_;

    pack_kernel<<<dim3(576), 256, 0, stream>>>(wq, bq, wk, bk, wv, bv, wo, W1, W2, Bs1);
    convT_kernel<<<dim3(64, 4, 16), 256, 0, stream>>>(x, f, xT, fT);
    qkv_gemm<<<dim3(1280), 256, 0, stream>>>(xT, fT, W1, Bs1, qT, kT, vv);
    attn_kernel<<<dim3(256), 512, 0, stream>>>(qT, kT, vv, aoT);
    out_gemm<<<dim3(1024), 256, 0, stream>>>(aoT, W2, bo, gamma, x, out);
}

// Round 10
// 159.618 us; speedup vs baseline: 1.0652x; 1.0652x over previous
//
#include <hip/hip_runtime.h>
#include <hip/hip_bf16.h>
#include <math.h>

#define B_  8
#define C_  256
#define CR_ 32
#define N_  4096

typedef __attribute__((ext_vector_type(8)))  short bf16x8;   // 8 bf16 = 4 VGPR
typedef __attribute__((ext_vector_type(16))) float f32x16;   // MFMA 32x32 acc
typedef __attribute__((ext_vector_type(4)))  int   int4v;

__device__ inline unsigned short f2b(float x) {
    __hip_bfloat16 h = __float2bfloat16(x);
    return __builtin_bit_cast(unsigned short, h);
}

// async 16B global->LDS (wave-uniform LDS base + lane*16; per-lane global src)
#define GLL16(gsrc, ldst) \
    __builtin_amdgcn_global_load_lds((const __attribute__((address_space(1))) void*)(gsrc), \
                                     (__attribute__((address_space(3))) void*)(ldst), 16, 0, 0)

// ---------------------------------------------------------------------------
// Kernel 0: pack weights to bf16.
//   W1[320][256]: rows 0-31 wq*log2e | 32-63 wk | 64-319 wv;  Bs1[320] fp32
//   W2[256][256]: wo
// ---------------------------------------------------------------------------
__global__ void pack_kernel(
    const float* __restrict__ wq, const float* __restrict__ bq,
    const float* __restrict__ wk, const float* __restrict__ bk,
    const float* __restrict__ wv, const float* __restrict__ bv,
    const float* __restrict__ wo,
    unsigned short* __restrict__ W1, unsigned short* __restrict__ W2,
    float* __restrict__ Bs1)
{
    const int r = blockIdx.x, t = threadIdx.x;
    const float L2E = 1.44269504088896340736f;
    if (r < 320) {
        float w;
        if (r < 32)      w = wq[r * C_ + t] * L2E;
        else if (r < 64) w = wk[(r - 32) * C_ + t];
        else             w = wv[(r - 64) * C_ + t];
        W1[r * C_ + t] = f2b(w);
        if (t == 0)
            Bs1[r] = (r < 32) ? bq[r] * L2E : ((r < 64) ? bk[r - 32] : bv[r - 64]);
    } else {
        W2[(r - 320) * C_ + t] = f2b(wo[(r - 320) * C_ + t]);
    }
}

// ---------------------------------------------------------------------------
// Kernel 1: transpose+convert  x,f fp32 [C,N] -> xT,fT bf16 [N,C].
// ---------------------------------------------------------------------------
__global__ __launch_bounds__(256) void convT_kernel(
    const float* __restrict__ x, const float* __restrict__ f,
    unsigned short* __restrict__ xT, unsigned short* __restrict__ fT)
{
    __shared__ float tile[64][65];
    const int t  = threadIdx.x;
    const int n0 = blockIdx.x * 64;
    const int c0 = blockIdx.y * 64;
    const int z  = blockIdx.z;
    const int b  = z >> 1;
    const float* src = (z & 1) ? f : x;
    unsigned short* dst = (z & 1) ? fT : xT;
    const size_t so = (size_t)b * C_ * N_;

    #pragma unroll
    for (int it = 0; it < 4; ++it) {
        const int cl = it * 16 + (t >> 4);
        *(float4*)&tile[cl][(t & 15) * 4] =
            *(const float4*)&src[so + (size_t)(c0 + cl) * N_ + n0 + (t & 15) * 4];
    }
    __syncthreads();

    const int nl = t >> 2;
    const int cg = (t & 3) * 16;
    unsigned short* drow = dst + ((size_t)b * N_ + n0 + nl) * C_ + c0 + cg;
    int4v w0, w1;
    #pragma unroll
    for (int e = 0; e < 4; ++e)
        w0[e] = (int)(((unsigned)f2b(tile[cg + 2*e][nl])) |
                      (((unsigned)f2b(tile[cg + 2*e + 1][nl])) << 16));
    #pragma unroll
    for (int e = 0; e < 4; ++e)
        w1[e] = (int)(((unsigned)f2b(tile[cg + 8 + 2*e][nl])) |
                      (((unsigned)f2b(tile[cg + 9 + 2*e][nl])) << 16));
    *(int4v*)(drow)     = w0;
    *(int4v*)(drow + 8) = w1;
}

// ---------------------------------------------------------------------------
// Shared MFMA GEMM mainloop (unchanged from R4).
// ---------------------------------------------------------------------------
__device__ __forceinline__ void gemm_mainloop(
    const unsigned short* __restrict__ Asrc,
    const unsigned short* __restrict__ Bsrc,
    unsigned short (*Ab)[32 * 32], unsigned short (*Bb)[256 * 32],
    int w, int l, f32x16& acc0, f32x16& acc1)
{
    const int jl = l & 31, hi = l >> 5;
    const int fj = (jl >> 1) & 3;

#define STAGE(KK, BUF) { \
    _Pragma("unroll") \
    for (int p = 0; p < 4; ++p) { \
        const int idx = p * 256 + w * 64 + l; \
        const int row = idx >> 2, slot = idx & 3; \
        GLL16(Bsrc + (size_t)row * 256 + (KK) * 32 + (slot ^ ((row >> 1) & 3)) * 8, \
              Bb[BUF] + (size_t)(p * 256 + w * 64) * 8); \
    } \
    if (w == 0) { \
        _Pragma("unroll") \
        for (int qq = 0; qq < 2; ++qq) { \
            const int idx = qq * 64 + l; \
            const int row = idx >> 2, slot = idx & 3; \
            GLL16(Asrc + (size_t)row * 256 + (KK) * 32 + (slot ^ ((row >> 1) & 3)) * 8, \
                  Ab[BUF] + (size_t)(qq * 64) * 8); \
        } \
    } }

    STAGE(0, 0)
    __syncthreads();

    for (int kk = 0; kk < 8; ++kk) {
        const int cur = kk & 1;
        if (kk < 7) STAGE(kk + 1, cur ^ 1)

        const unsigned short* Ac = Ab[cur];
        const unsigned short* Bc = Bb[cur];
        const bf16x8 af0 = *(const bf16x8*)&Ac[jl * 32 + ((hi ^ fj) * 8)];
        const bf16x8 af1 = *(const bf16x8*)&Ac[jl * 32 + (((2 + hi) ^ fj) * 8)];
        const int r0 = w * 64 + jl, r1 = w * 64 + 32 + jl;
        const bf16x8 bf00 = *(const bf16x8*)&Bc[r0 * 32 + ((hi ^ fj) * 8)];
        const bf16x8 bf01 = *(const bf16x8*)&Bc[r0 * 32 + (((2 + hi) ^ fj) * 8)];
        const bf16x8 bf10 = *(const bf16x8*)&Bc[r1 * 32 + ((hi ^ fj) * 8)];
        const bf16x8 bf11 = *(const bf16x8*)&Bc[r1 * 32 + (((2 + hi) ^ fj) * 8)];

        acc0 = __builtin_amdgcn_mfma_f32_32x32x16_bf16(af0, bf00, acc0, 0, 0, 0);
        acc0 = __builtin_amdgcn_mfma_f32_32x32x16_bf16(af1, bf01, acc0, 0, 0, 0);
        acc1 = __builtin_amdgcn_mfma_f32_32x32x16_bf16(af0, bf10, acc1, 0, 0, 0);
        acc1 = __builtin_amdgcn_mfma_f32_32x32x16_bf16(af1, bf11, acc1, 0, 0, 0);
        __syncthreads();
    }
#undef STAGE
}

// ---------------------------------------------------------------------------
// Kernel 2: QKV projection GEMM (unchanged from R4).
// ---------------------------------------------------------------------------
__global__ __launch_bounds__(256) void qkv_gemm(
    const unsigned short* __restrict__ xT, const unsigned short* __restrict__ fT,
    const unsigned short* __restrict__ W1, const float* __restrict__ Bs1,
    unsigned short* __restrict__ qT, unsigned short* __restrict__ kT,
    unsigned short* __restrict__ v)
{
    __shared__ __align__(16) unsigned short Ab[2][32 * 32];
    __shared__ __align__(16) unsigned short Bb[2][256 * 32];

    const int t = threadIdx.x;
    const int w = t >> 6, l = t & 63;
    const int jl = l & 31, hi = l >> 5;
    const int bid = blockIdx.x;
    const int b  = bid & 7;
    const int r_ = bid >> 3;
    const int mt = r_ % 10;
    const int nt = r_ / 10;

    const unsigned short* Asrc = W1 + (size_t)mt * 32 * C_;
    const unsigned short* Bsrc = ((mt == 0) ? xT : fT) + (size_t)b * N_ * C_
                               + (size_t)nt * 256 * C_;

    f32x16 acc0 = (f32x16)0.f, acc1 = (f32x16)0.f;
    gemm_mainloop(Asrc, Bsrc, Ab, Bb, w, l, acc0, acc1);

    const int m0 = mt * 32;
    const int nb = nt * 256 + w * 64;
    if (mt <= 1) {
        unsigned short* dst = ((mt == 0) ? qT : kT) + (size_t)b * N_ * CR_;
        #pragma unroll
        for (int ns = 0; ns < 2; ++ns) {
            const f32x16& A = ns ? acc1 : acc0;
            const int n = nb + ns * 32 + jl;
            #pragma unroll
            for (int r4 = 0; r4 < 4; ++r4) {
                const float4 bi = *(const float4*)&Bs1[m0 + r4 * 8 + 4 * hi];
                const unsigned int d0 = (unsigned)f2b(A[r4*4+0] + bi.x) |
                                        ((unsigned)f2b(A[r4*4+1] + bi.y) << 16);
                const unsigned int d1 = (unsigned)f2b(A[r4*4+2] + bi.z) |
                                        ((unsigned)f2b(A[r4*4+3] + bi.w) << 16);
                *(uint2*)(dst + (size_t)n * CR_ + r4 * 8 + 4 * hi) = make_uint2(d0, d1);
            }
        }
    } else {
        unsigned short* dst = v + (size_t)b * C_ * N_;
        #pragma unroll
        for (int ns = 0; ns < 2; ++ns) {
            const f32x16& A = ns ? acc1 : acc0;
            const int n = nb + ns * 32 + jl;
            #pragma unroll
            for (int r4 = 0; r4 < 4; ++r4) {
                const float4 bi = *(const float4*)&Bs1[m0 + r4 * 8 + 4 * hi];
                #pragma unroll
                for (int e = 0; e < 4; ++e) {
                    const int c = m0 - 64 + e + 8 * r4 + 4 * hi;
                    dst[(size_t)c * N_ + n] = f2b(A[r4*4+e] + ((const float*)&bi)[e]);
                }
            }
        }
    }
}

// ---------------------------------------------------------------------------
// Kernel 3: MFMA flash attention v8 — V-read-duplication reduction.
// Grid 256 (1 block/CU), block 512 = 8 waves = 2 ig x 2 cs x 2 js.
// Wave = 64i (2 subtiles) x 128c x its js-half (32 j) of each 64-j tile:
// V fragments shared across the 2 i-subtiles -> V LDS-read dup 4x -> 2x.
// js partial sums (linear, streaming softmax) merged ONCE at epilogue via
// LDS. 8 accs/wave (~128 VGPR) - no launch_bounds cap (R5 lesson).
// K register-pipelined from global (L1-resident); V staging as R8.
// ---------------------------------------------------------------------------
__device__ inline void softmax_tile(const f32x16& s, float& lsum,
                                    bf16x8& pf0, bf16x8& pf1)
{
    float ps = 0.f;
    int wd[8];
    #pragma unroll
    for (int r = 0; r < 16; r += 2) {
        float e0 = __builtin_amdgcn_exp2f(s[r]);
        float e1 = __builtin_amdgcn_exp2f(s[r + 1]);
        ps += e0 + e1;
        int pk;
        asm("v_cvt_pk_bf16_f32 %0, %1, %2" : "=v"(pk) : "v"(e0), "v"(e1));
        wd[r >> 1] = pk;
    }
    lsum += ps;                       // per-lane partial; merged after the loop
    asm volatile("v_permlane32_swap_b32 %0, %1" : "+v"(wd[0]), "+v"(wd[2]));
    asm volatile("v_permlane32_swap_b32 %0, %1" : "+v"(wd[1]), "+v"(wd[3]));
    asm volatile("v_permlane32_swap_b32 %0, %1" : "+v"(wd[4]), "+v"(wd[6]));
    asm volatile("v_permlane32_swap_b32 %0, %1" : "+v"(wd[5]), "+v"(wd[7]));
    union { int4v i4; bf16x8 h8; } u0, u1;
    u0.i4 = (int4v){ wd[0], wd[1], wd[2], wd[3] };   // k = j0 .. j0+15
    u1.i4 = (int4v){ wd[4], wd[5], wd[6], wd[7] };   // k = j0+16 .. j0+31
    pf0 = u0.h8; pf1 = u1.h8;
}

__global__ __launch_bounds__(512) void attn_kernel(
    const unsigned short* __restrict__ qT, const unsigned short* __restrict__ kT,
    const unsigned short* __restrict__ v, unsigned short* __restrict__ aoT)
{
    __shared__ __align__(16) unsigned short Vt[2][256 * 64];  // 2 x 32 KB
    __shared__ float lsx[2][512];                             // 4 KB

    const int t  = threadIdx.x;
    const int w  = t >> 6;
    const int l  = t & 63;
    const int jl = l & 31;
    const int hi = l >> 5;
    const int js = w & 1;              // j-half of each 64-j tile
    const int ig = (w >> 1) & 1;       // 64-i subtile pair
    const int cs = w >> 2;             // 128-channel half

    const int bid = blockIdx.x;
    const int b   = bid & 7;           // XCD-local batch
    const int it  = bid >> 3;          // 0..31
    const int i0  = it * 128 + ig * 64;

    const unsigned short* qTb = qT + (size_t)b * N_ * CR_;
    const unsigned short* kTb = kT + (size_t)b * N_ * CR_;
    const unsigned short* vb  = v  + (size_t)b * C_ * N_;

    // Q fragments for both 32-i subtiles (B operand: col=i, k=d)
    const bf16x8 q00 = *(const bf16x8*)(qTb + (size_t)(i0 + jl) * CR_ + hi * 8);
    const bf16x8 q01 = *(const bf16x8*)(qTb + (size_t)(i0 + jl) * CR_ + 16 + hi * 8);
    const bf16x8 q10 = *(const bf16x8*)(qTb + (size_t)(i0 + 32 + jl) * CR_ + hi * 8);
    const bf16x8 q11 = *(const bf16x8*)(qTb + (size_t)(i0 + 32 + jl) * CR_ + 16 + hi * 8);

    // K rows for this wave's js-half: j = jt*64 + js*32 + jl
    const unsigned short* kln = kTb + (size_t)(js * 32 + jl) * CR_ + hi * 8;

    // ---- V staging (linear LDS dest + inverse-swizzled global src), as R8 ----
    const unsigned short* vsrc[4];
    int vdst[4];
    #pragma unroll
    for (int p = 0; p < 4; ++p) {
        const int idx = p * 512 + t;
        const int row = idx >> 3, slot = idx & 7;
        vsrc[p] = vb + (size_t)row * N_ + (slot ^ (row & 7)) * 8;
        vdst[p] = idx * 8;             // shorts (linear)
    }

    f32x16 a00 = (f32x16)0.f, a01 = (f32x16)0.f, a02 = (f32x16)0.f, a03 = (f32x16)0.f;
    f32x16 a10 = (f32x16)0.f, a11 = (f32x16)0.f, a12 = (f32x16)0.f, a13 = (f32x16)0.f;
    float ls0 = 0.f, ls1 = 0.f;

    // prologue: stage V tile 0; load K js-half 0 into registers
    #pragma unroll
    for (int p = 0; p < 4; ++p) GLL16(vsrc[p], &Vt[0][vdst[p]]);
    bf16x8 kc0 = *(const bf16x8*)(kln);
    bf16x8 kc1 = *(const bf16x8*)(kln + 16);
    __syncthreads();

    // V read offsets: row = c, chunk = js*4 + kk*2 + hi, slot = chunk^(row&7)
    int voff0[4], voff1[4];
    #pragma unroll
    for (int ct = 0; ct < 4; ++ct) {
        const int rv = cs * 128 + ct * 32 + jl;
        voff0[ct] = rv * 64 + (((js * 4 + hi)     ^ (rv & 7)) * 8);
        voff1[ct] = rv * 64 + (((js * 4 + 2 + hi) ^ (rv & 7)) * 8);
    }

    for (int jt = 0; jt < N_ / 64; ++jt) {
        const int cur = jt & 1;
        bf16x8 kn0 = kc0, kn1 = kc1;
        if (jt + 1 < N_ / 64) {        // prefetch next tile (V->LDS, K->regs)
            const size_t jn = (size_t)(jt + 1) * 64;
            #pragma unroll
            for (int p = 0; p < 4; ++p) GLL16(vsrc[p] + jn, &Vt[cur ^ 1][vdst[p]]);
            kn0 = *(const bf16x8*)(kln + jn * CR_);
            kn1 = *(const bf16x8*)(kln + jn * CR_ + 16);
        }

        // ---- S^T for both i-subtiles: A = K (row=j), B = Q (col=i) ----
        __builtin_amdgcn_s_setprio(1);
        f32x16 s0 = (f32x16)0.f, s1 = (f32x16)0.f;
        s0 = __builtin_amdgcn_mfma_f32_32x32x16_bf16(kc0, q00, s0, 0, 0, 0);
        s0 = __builtin_amdgcn_mfma_f32_32x32x16_bf16(kc1, q01, s0, 0, 0, 0);
        s1 = __builtin_amdgcn_mfma_f32_32x32x16_bf16(kc0, q10, s1, 0, 0, 0);
        s1 = __builtin_amdgcn_mfma_f32_32x32x16_bf16(kc1, q11, s1, 0, 0, 0);
        __builtin_amdgcn_s_setprio(0);

        bf16x8 p00, p01, p10, p11;
        softmax_tile(s0, ls0, p00, p01);
        softmax_tile(s1, ls1, p10, p11);

        // ---- PV: V fragments SHARED by both i-subtiles ----
        __builtin_amdgcn_s_setprio(1);
#define PVSTEP(CT, AA, AB) { \
        const bf16x8 v0_ = *(const bf16x8*)&Vt[cur][voff0[CT]]; \
        const bf16x8 v1_ = *(const bf16x8*)&Vt[cur][voff1[CT]]; \
        AA = __builtin_amdgcn_mfma_f32_32x32x16_bf16(v0_, p00, AA, 0, 0, 0); \
        AA = __builtin_amdgcn_mfma_f32_32x32x16_bf16(v1_, p01, AA, 0, 0, 0); \
        AB = __builtin_amdgcn_mfma_f32_32x32x16_bf16(v0_, p10, AB, 0, 0, 0); \
        AB = __builtin_amdgcn_mfma_f32_32x32x16_bf16(v1_, p11, AB, 0, 0, 0); }
        PVSTEP(0, a00, a10)
        PVSTEP(1, a01, a11)
        PVSTEP(2, a02, a12)
        PVSTEP(3, a03, a13)
#undef PVSTEP
        __builtin_amdgcn_s_setprio(0);

        __syncthreads();   // staged tile ready; cur buffer free for overwrite
        kc0 = kn0; kc1 = kn1;
    }

    // ---- merge lane-halves of lsums ----
    ls0 += __shfl_xor(ls0, 32);
    ls1 += __shfl_xor(ls1, 32);

    // ---- cross-js merge: lsums via lsx; accs via Vt (2 rounds) ----
    lsx[0][w * 64 + l] = ls0;
    lsx[1][w * 64 + l] = ls1;
    float* As = (float*)&Vt[0][0];     // 16384 floats
    const int base = (w >> 1) * 4096;  // same slot for js-partners

#define STORE_ACC(A, CT) { _Pragma("unroll") \
    for (int r = 0; r < 16; ++r) As[base + (CT) * 1024 + r * 64 + l] = A[r]; }
#define ADD_ACC(A, CT) { _Pragma("unroll") \
    for (int r = 0; r < 16; ++r) A[r] += As[base + (CT) * 1024 + r * 64 + l]; }

    __syncthreads();
    if (js == 1) { STORE_ACC(a00, 0) STORE_ACC(a01, 1) STORE_ACC(a02, 2) STORE_ACC(a03, 3) }
    __syncthreads();
    if (js == 0) { ADD_ACC(a00, 0) ADD_ACC(a01, 1) ADD_ACC(a02, 2) ADD_ACC(a03, 3) }
    __syncthreads();
    if (js == 1) { STORE_ACC(a10, 0) STORE_ACC(a11, 1) STORE_ACC(a12, 2) STORE_ACC(a13, 3) }
    __syncthreads();
    if (js == 0) {
        ADD_ACC(a10, 0) ADD_ACC(a11, 1) ADD_ACC(a12, 2) ADD_ACC(a13, 3)

        const float ra = 1.f / (ls0 + lsx[0][(w + 1) * 64 + l]);
        const float rb = 1.f / (ls1 + lsx[1][(w + 1) * 64 + l]);
        unsigned short* aoTb = aoT + (size_t)b * N_ * C_;
        const int ica = i0 + jl, icb = i0 + 32 + jl;
#define EPI(ACC, CT, COL, RL) { _Pragma("unroll") \
    for (int r4 = 0; r4 < 4; ++r4) { \
        const unsigned int d0 = (unsigned)f2b(ACC[r4*4+0] * (RL)) | \
                                ((unsigned)f2b(ACC[r4*4+1] * (RL)) << 16); \
        const unsigned int d1 = (unsigned)f2b(ACC[r4*4+2] * (RL)) | \
                                ((unsigned)f2b(ACC[r4*4+3] * (RL)) << 16); \
        *(uint2*)(aoTb + (size_t)(COL) * C_ + cs * 128 + (CT) * 32 + r4 * 8 + 4 * hi) \
            = make_uint2(d0, d1); } }
        EPI(a00, 0, ica, ra)
        EPI(a01, 1, ica, ra)
        EPI(a02, 2, ica, ra)
        EPI(a03, 3, ica, ra)
        EPI(a10, 0, icb, rb)
        EPI(a11, 1, icb, rb)
        EPI(a12, 2, icb, rb)
        EPI(a13, 3, icb, rb)
#undef EPI
    }
#undef STORE_ACC
#undef ADD_ACC
}

// ---------------------------------------------------------------------------
// Kernel 4: output projection GEMM + gated residual (unchanged from R4).
// ---------------------------------------------------------------------------
__global__ __launch_bounds__(256) void out_gemm(
    const unsigned short* __restrict__ aoT, const unsigned short* __restrict__ W2,
    const float* __restrict__ bo, const float* __restrict__ gamma,
    const float* __restrict__ x, float* __restrict__ out)
{
    __shared__ __align__(16) unsigned short Ab[2][32 * 32];
    __shared__ __align__(16) unsigned short Bb[2][256 * 32];

    const int t = threadIdx.x;
    const int w = t >> 6, l = t & 63;
    const int jl = l & 31, hi = l >> 5;
    const int bid = blockIdx.x;
    const int b  = bid & 7;
    const int r_ = bid >> 3;
    const int mt = r_ & 7;
    const int nt = r_ >> 3;

    const unsigned short* Asrc = W2 + (size_t)mt * 32 * C_;
    const unsigned short* Bsrc = aoT + (size_t)b * N_ * C_ + (size_t)nt * 256 * C_;

    f32x16 acc0 = (f32x16)0.f, acc1 = (f32x16)0.f;
    gemm_mainloop(Asrc, Bsrc, Ab, Bb, w, l, acc0, acc1);

    const float gm = gamma[0];
    const int m0 = mt * 32;
    const int nb = nt * 256 + w * 64;
    #pragma unroll
    for (int ns = 0; ns < 2; ++ns) {
        const f32x16& A = ns ? acc1 : acc0;
        const int n = nb + ns * 32 + jl;
        #pragma unroll
        for (int r4 = 0; r4 < 4; ++r4) {
            const float4 bi = *(const float4*)&bo[m0 + r4 * 8 + 4 * hi];
            #pragma unroll
            for (int e = 0; e < 4; ++e) {
                const int c = m0 + e + 8 * r4 + 4 * hi;
                const size_t o = ((size_t)b * C_ + c) * N_ + n;
                out[o] = fmaf(gm, A[r4*4+e] + ((const float*)&bi)[e], x[o]);
            }
        }
    }
}

// ---------------------------------------------------------------------------
extern "C" void kernel_launch(void* const* d_in, const int* in_sizes, int n_in,
                              void* d_out, int out_size, void* d_ws, size_t ws_size,
                              hipStream_t stream)
{
    const float* x     = (const float*)d_in[0];
    const float* f     = (const float*)d_in[1];
    const float* wq    = (const float*)d_in[2];
    const float* bq    = (const float*)d_in[3];
    const float* wk    = (const float*)d_in[4];
    const float* bk    = (const float*)d_in[5];
    const float* wv    = (const float*)d_in[6];
    const float* bv    = (const float*)d_in[7];
    const float* wo    = (const float*)d_in[8];
    const float* bo    = (const float*)d_in[9];
    const float* gamma = (const float*)d_in[10];
    float* out = (float*)d_out;

    float* Bs1 = (float*)d_ws;
    unsigned short* W1 = (unsigned short*)(Bs1 + 320);
    unsigned short* W2 = W1 + 320 * C_;
    unsigned short* xT = W2 + 256 * C_;
    unsigned short* fT = xT + (size_t)B_ * N_ * C_;
    unsigned short* qT = fT + (size_t)B_ * N_ * C_;
    unsigned short* kT = qT + (size_t)B_ * N_ * CR_;
    unsigned short* vv = kT + (size_t)B_ * N_ * CR_;
    unsigned short* aoT = vv + (size_t)B_ * C_ * N_;

    pack_kernel<<<dim3(576), 256, 0, stream>>>(wq, bq, wk, bk, wv, bv, wo, W1, W2, Bs1);
    convT_kernel<<<dim3(64, 4, 16), 256, 0, stream>>>(x, f, xT, fT);
    qkv_gemm<<<dim3(1280), 256, 0, stream>>>(xT, fT, W1, Bs1, qT, kT, vv);
    attn_kernel<<<dim3(256), 512, 0, stream>>>(qT, kT, vv, aoT);
    out_gemm<<<dim3(1024), 256, 0, stream>>>(aoT, W2, bo, gamma, x, out);
}

// Round 11
// 144.829 us; speedup vs baseline: 1.1740x; 1.1021x over previous
//
#include <hip/hip_runtime.h>
#include <hip/hip_bf16.h>
#include <math.h>

#define B_  8
#define C_  256
#define CR_ 32
#define N_  4096

typedef __attribute__((ext_vector_type(8)))  short bf16x8;   // 8 bf16 = 4 VGPR
typedef __attribute__((ext_vector_type(16))) float f32x16;   // MFMA 32x32 acc
typedef __attribute__((ext_vector_type(4)))  int   int4v;

__device__ inline unsigned short f2b(float x) {
    __hip_bfloat16 h = __float2bfloat16(x);
    return __builtin_bit_cast(unsigned short, h);
}

// async 16B global->LDS (wave-uniform LDS base + lane*16; per-lane global src)
#define GLL16(gsrc, ldst) \
    __builtin_amdgcn_global_load_lds((const __attribute__((address_space(1))) void*)(gsrc), \
                                     (__attribute__((address_space(3))) void*)(ldst), 16, 0, 0)

// ---------------------------------------------------------------------------
// Kernel 0: pack weights to bf16.
//   W1[320][256]: rows 0-31 wq*log2e | 32-63 wk | 64-319 wv;  Bs1[320] fp32
//   W2[256][256]: wo
// ---------------------------------------------------------------------------
__global__ void pack_kernel(
    const float* __restrict__ wq, const float* __restrict__ bq,
    const float* __restrict__ wk, const float* __restrict__ bk,
    const float* __restrict__ wv, const float* __restrict__ bv,
    const float* __restrict__ wo,
    unsigned short* __restrict__ W1, unsigned short* __restrict__ W2,
    float* __restrict__ Bs1)
{
    const int r = blockIdx.x, t = threadIdx.x;
    const float L2E = 1.44269504088896340736f;
    if (r < 320) {
        float w;
        if (r < 32)      w = wq[r * C_ + t] * L2E;
        else if (r < 64) w = wk[(r - 32) * C_ + t];
        else             w = wv[(r - 64) * C_ + t];
        W1[r * C_ + t] = f2b(w);
        if (t == 0)
            Bs1[r] = (r < 32) ? bq[r] * L2E : ((r < 64) ? bk[r - 32] : bv[r - 64]);
    } else {
        W2[(r - 320) * C_ + t] = f2b(wo[(r - 320) * C_ + t]);
    }
}

// ---------------------------------------------------------------------------
// Kernel 1: transpose+convert  x,f fp32 [C,N] -> xT,fT bf16 [N,C].
// ---------------------------------------------------------------------------
__global__ __launch_bounds__(256) void convT_kernel(
    const float* __restrict__ x, const float* __restrict__ f,
    unsigned short* __restrict__ xT, unsigned short* __restrict__ fT)
{
    __shared__ float tile[64][65];
    const int t  = threadIdx.x;
    const int n0 = blockIdx.x * 64;
    const int c0 = blockIdx.y * 64;
    const int z  = blockIdx.z;
    const int b  = z >> 1;
    const float* src = (z & 1) ? f : x;
    unsigned short* dst = (z & 1) ? fT : xT;
    const size_t so = (size_t)b * C_ * N_;

    #pragma unroll
    for (int it = 0; it < 4; ++it) {
        const int cl = it * 16 + (t >> 4);
        *(float4*)&tile[cl][(t & 15) * 4] =
            *(const float4*)&src[so + (size_t)(c0 + cl) * N_ + n0 + (t & 15) * 4];
    }
    __syncthreads();

    const int nl = t >> 2;
    const int cg = (t & 3) * 16;
    unsigned short* drow = dst + ((size_t)b * N_ + n0 + nl) * C_ + c0 + cg;
    int4v w0, w1;
    #pragma unroll
    for (int e = 0; e < 4; ++e)
        w0[e] = (int)(((unsigned)f2b(tile[cg + 2*e][nl])) |
                      (((unsigned)f2b(tile[cg + 2*e + 1][nl])) << 16));
    #pragma unroll
    for (int e = 0; e < 4; ++e)
        w1[e] = (int)(((unsigned)f2b(tile[cg + 8 + 2*e][nl])) |
                      (((unsigned)f2b(tile[cg + 9 + 2*e][nl])) << 16));
    *(int4v*)(drow)     = w0;
    *(int4v*)(drow + 8) = w1;
}

// ---------------------------------------------------------------------------
// Shared MFMA GEMM mainloop (unchanged from R4).
// ---------------------------------------------------------------------------
__device__ __forceinline__ void gemm_mainloop(
    const unsigned short* __restrict__ Asrc,
    const unsigned short* __restrict__ Bsrc,
    unsigned short (*Ab)[32 * 32], unsigned short (*Bb)[256 * 32],
    int w, int l, f32x16& acc0, f32x16& acc1)
{
    const int jl = l & 31, hi = l >> 5;
    const int fj = (jl >> 1) & 3;

#define STAGE(KK, BUF) { \
    _Pragma("unroll") \
    for (int p = 0; p < 4; ++p) { \
        const int idx = p * 256 + w * 64 + l; \
        const int row = idx >> 2, slot = idx & 3; \
        GLL16(Bsrc + (size_t)row * 256 + (KK) * 32 + (slot ^ ((row >> 1) & 3)) * 8, \
              Bb[BUF] + (size_t)(p * 256 + w * 64) * 8); \
    } \
    if (w == 0) { \
        _Pragma("unroll") \
        for (int qq = 0; qq < 2; ++qq) { \
            const int idx = qq * 64 + l; \
            const int row = idx >> 2, slot = idx & 3; \
            GLL16(Asrc + (size_t)row * 256 + (KK) * 32 + (slot ^ ((row >> 1) & 3)) * 8, \
                  Ab[BUF] + (size_t)(qq * 64) * 8); \
        } \
    } }

    STAGE(0, 0)
    __syncthreads();

    for (int kk = 0; kk < 8; ++kk) {
        const int cur = kk & 1;
        if (kk < 7) STAGE(kk + 1, cur ^ 1)

        const unsigned short* Ac = Ab[cur];
        const unsigned short* Bc = Bb[cur];
        const bf16x8 af0 = *(const bf16x8*)&Ac[jl * 32 + ((hi ^ fj) * 8)];
        const bf16x8 af1 = *(const bf16x8*)&Ac[jl * 32 + (((2 + hi) ^ fj) * 8)];
        const int r0 = w * 64 + jl, r1 = w * 64 + 32 + jl;
        const bf16x8 bf00 = *(const bf16x8*)&Bc[r0 * 32 + ((hi ^ fj) * 8)];
        const bf16x8 bf01 = *(const bf16x8*)&Bc[r0 * 32 + (((2 + hi) ^ fj) * 8)];
        const bf16x8 bf10 = *(const bf16x8*)&Bc[r1 * 32 + ((hi ^ fj) * 8)];
        const bf16x8 bf11 = *(const bf16x8*)&Bc[r1 * 32 + (((2 + hi) ^ fj) * 8)];

        acc0 = __builtin_amdgcn_mfma_f32_32x32x16_bf16(af0, bf00, acc0, 0, 0, 0);
        acc0 = __builtin_amdgcn_mfma_f32_32x32x16_bf16(af1, bf01, acc0, 0, 0, 0);
        acc1 = __builtin_amdgcn_mfma_f32_32x32x16_bf16(af0, bf10, acc1, 0, 0, 0);
        acc1 = __builtin_amdgcn_mfma_f32_32x32x16_bf16(af1, bf11, acc1, 0, 0, 0);
        __syncthreads();
    }
#undef STAGE
}

// ---------------------------------------------------------------------------
// Kernel 2: QKV projection GEMM (unchanged from R4).
// ---------------------------------------------------------------------------
__global__ __launch_bounds__(256) void qkv_gemm(
    const unsigned short* __restrict__ xT, const unsigned short* __restrict__ fT,
    const unsigned short* __restrict__ W1, const float* __restrict__ Bs1,
    unsigned short* __restrict__ qT, unsigned short* __restrict__ kT,
    unsigned short* __restrict__ v)
{
    __shared__ __align__(16) unsigned short Ab[2][32 * 32];
    __shared__ __align__(16) unsigned short Bb[2][256 * 32];

    const int t = threadIdx.x;
    const int w = t >> 6, l = t & 63;
    const int jl = l & 31, hi = l >> 5;
    const int bid = blockIdx.x;
    const int b  = bid & 7;
    const int r_ = bid >> 3;
    const int mt = r_ % 10;
    const int nt = r_ / 10;

    const unsigned short* Asrc = W1 + (size_t)mt * 32 * C_;
    const unsigned short* Bsrc = ((mt == 0) ? xT : fT) + (size_t)b * N_ * C_
                               + (size_t)nt * 256 * C_;

    f32x16 acc0 = (f32x16)0.f, acc1 = (f32x16)0.f;
    gemm_mainloop(Asrc, Bsrc, Ab, Bb, w, l, acc0, acc1);

    const int m0 = mt * 32;
    const int nb = nt * 256 + w * 64;
    if (mt <= 1) {
        unsigned short* dst = ((mt == 0) ? qT : kT) + (size_t)b * N_ * CR_;
        #pragma unroll
        for (int ns = 0; ns < 2; ++ns) {
            const f32x16& A = ns ? acc1 : acc0;
            const int n = nb + ns * 32 + jl;
            #pragma unroll
            for (int r4 = 0; r4 < 4; ++r4) {
                const float4 bi = *(const float4*)&Bs1[m0 + r4 * 8 + 4 * hi];
                const unsigned int d0 = (unsigned)f2b(A[r4*4+0] + bi.x) |
                                        ((unsigned)f2b(A[r4*4+1] + bi.y) << 16);
                const unsigned int d1 = (unsigned)f2b(A[r4*4+2] + bi.z) |
                                        ((unsigned)f2b(A[r4*4+3] + bi.w) << 16);
                *(uint2*)(dst + (size_t)n * CR_ + r4 * 8 + 4 * hi) = make_uint2(d0, d1);
            }
        }
    } else {
        unsigned short* dst = v + (size_t)b * C_ * N_;
        #pragma unroll
        for (int ns = 0; ns < 2; ++ns) {
            const f32x16& A = ns ? acc1 : acc0;
            const int n = nb + ns * 32 + jl;
            #pragma unroll
            for (int r4 = 0; r4 < 4; ++r4) {
                const float4 bi = *(const float4*)&Bs1[m0 + r4 * 8 + 4 * hi];
                #pragma unroll
                for (int e = 0; e < 4; ++e) {
                    const int c = m0 - 64 + e + 8 * r4 + 4 * hi;
                    dst[(size_t)c * N_ + n] = f2b(A[r4*4+e] + ((const float*)&bi)[e]);
                }
            }
        }
    }
}

// ---------------------------------------------------------------------------
// Kernel 3: MFMA flash attention v9 = R10 core + FUSED output projection.
// Grid 256 (1 block/CU), block 512 = 8 waves = 2 ig x 2 cs x 2 js.
// Main loop identical to R10. Epilogue: js-merge (as R10), then js0 waves
// write the normalized 128n x 256c bf16 ao-tile into LDS (Vt reuse, chunk-XOR
// swizzle q^(n&7)), then ALL 8 waves compute out = gamma*(wo.ao + bo) + x
// for this i-tile directly (A = W2 rows from L2, B = ao-tile from LDS).
// Kills out_gemm kernel + the 33.6 MB aoT HBM round-trip.
// ---------------------------------------------------------------------------
__device__ inline void softmax_tile(const f32x16& s, float& lsum,
                                    bf16x8& pf0, bf16x8& pf1)
{
    float ps = 0.f;
    int wd[8];
    #pragma unroll
    for (int r = 0; r < 16; r += 2) {
        float e0 = __builtin_amdgcn_exp2f(s[r]);
        float e1 = __builtin_amdgcn_exp2f(s[r + 1]);
        ps += e0 + e1;
        int pk;
        asm("v_cvt_pk_bf16_f32 %0, %1, %2" : "=v"(pk) : "v"(e0), "v"(e1));
        wd[r >> 1] = pk;
    }
    lsum += ps;                       // per-lane partial; merged after the loop
    asm volatile("v_permlane32_swap_b32 %0, %1" : "+v"(wd[0]), "+v"(wd[2]));
    asm volatile("v_permlane32_swap_b32 %0, %1" : "+v"(wd[1]), "+v"(wd[3]));
    asm volatile("v_permlane32_swap_b32 %0, %1" : "+v"(wd[4]), "+v"(wd[6]));
    asm volatile("v_permlane32_swap_b32 %0, %1" : "+v"(wd[5]), "+v"(wd[7]));
    union { int4v i4; bf16x8 h8; } u0, u1;
    u0.i4 = (int4v){ wd[0], wd[1], wd[2], wd[3] };   // k = j0 .. j0+15
    u1.i4 = (int4v){ wd[4], wd[5], wd[6], wd[7] };   // k = j0+16 .. j0+31
    pf0 = u0.h8; pf1 = u1.h8;
}

__global__ __launch_bounds__(512) void attn_kernel(
    const unsigned short* __restrict__ qT, const unsigned short* __restrict__ kT,
    const unsigned short* __restrict__ v, const unsigned short* __restrict__ W2,
    const float* __restrict__ bo, const float* __restrict__ gamma,
    const float* __restrict__ x, float* __restrict__ out)
{
    __shared__ __align__(16) unsigned short Vt[2][256 * 64];  // 2 x 32 KB
    __shared__ float lsx[2][512];                             // 4 KB

    const int t  = threadIdx.x;
    const int w  = t >> 6;
    const int l  = t & 63;
    const int jl = l & 31;
    const int hi = l >> 5;
    const int js = w & 1;              // j-half of each 64-j tile
    const int ig = (w >> 1) & 1;       // 64-i subtile pair
    const int cs = w >> 2;             // 128-channel half

    const int bid = blockIdx.x;
    const int b   = bid & 7;           // XCD-local batch
    const int it  = bid >> 3;          // 0..31
    const int i0  = it * 128 + ig * 64;

    const unsigned short* qTb = qT + (size_t)b * N_ * CR_;
    const unsigned short* kTb = kT + (size_t)b * N_ * CR_;
    const unsigned short* vb  = v  + (size_t)b * C_ * N_;

    // Q fragments for both 32-i subtiles (B operand: col=i, k=d)
    const bf16x8 q00 = *(const bf16x8*)(qTb + (size_t)(i0 + jl) * CR_ + hi * 8);
    const bf16x8 q01 = *(const bf16x8*)(qTb + (size_t)(i0 + jl) * CR_ + 16 + hi * 8);
    const bf16x8 q10 = *(const bf16x8*)(qTb + (size_t)(i0 + 32 + jl) * CR_ + hi * 8);
    const bf16x8 q11 = *(const bf16x8*)(qTb + (size_t)(i0 + 32 + jl) * CR_ + 16 + hi * 8);

    // K rows for this wave's js-half: j = jt*64 + js*32 + jl
    const unsigned short* kln = kTb + (size_t)(js * 32 + jl) * CR_ + hi * 8;

    // ---- V staging (linear LDS dest + inverse-swizzled global src) ----
    const unsigned short* vsrc[4];
    int vdst[4];
    #pragma unroll
    for (int p = 0; p < 4; ++p) {
        const int idx = p * 512 + t;
        const int row = idx >> 3, slot = idx & 7;
        vsrc[p] = vb + (size_t)row * N_ + (slot ^ (row & 7)) * 8;
        vdst[p] = idx * 8;             // shorts (linear)
    }

    f32x16 a00 = (f32x16)0.f, a01 = (f32x16)0.f, a02 = (f32x16)0.f, a03 = (f32x16)0.f;
    f32x16 a10 = (f32x16)0.f, a11 = (f32x16)0.f, a12 = (f32x16)0.f, a13 = (f32x16)0.f;
    float ls0 = 0.f, ls1 = 0.f;

    // prologue: stage V tile 0; load K js-half 0 into registers
    #pragma unroll
    for (int p = 0; p < 4; ++p) GLL16(vsrc[p], &Vt[0][vdst[p]]);
    bf16x8 kc0 = *(const bf16x8*)(kln);
    bf16x8 kc1 = *(const bf16x8*)(kln + 16);
    __syncthreads();

    // V read offsets: row = c, chunk = js*4 + kk*2 + hi, slot = chunk^(row&7)
    int voff0[4], voff1[4];
    #pragma unroll
    for (int ct = 0; ct < 4; ++ct) {
        const int rv = cs * 128 + ct * 32 + jl;
        voff0[ct] = rv * 64 + (((js * 4 + hi)     ^ (rv & 7)) * 8);
        voff1[ct] = rv * 64 + (((js * 4 + 2 + hi) ^ (rv & 7)) * 8);
    }

    for (int jt = 0; jt < N_ / 64; ++jt) {
        const int cur = jt & 1;
        bf16x8 kn0 = kc0, kn1 = kc1;
        if (jt + 1 < N_ / 64) {        // prefetch next tile (V->LDS, K->regs)
            const size_t jn = (size_t)(jt + 1) * 64;
            #pragma unroll
            for (int p = 0; p < 4; ++p) GLL16(vsrc[p] + jn, &Vt[cur ^ 1][vdst[p]]);
            kn0 = *(const bf16x8*)(kln + jn * CR_);
            kn1 = *(const bf16x8*)(kln + jn * CR_ + 16);
        }

        // ---- S^T for both i-subtiles: A = K (row=j), B = Q (col=i) ----
        __builtin_amdgcn_s_setprio(1);
        f32x16 s0 = (f32x16)0.f, s1 = (f32x16)0.f;
        s0 = __builtin_amdgcn_mfma_f32_32x32x16_bf16(kc0, q00, s0, 0, 0, 0);
        s0 = __builtin_amdgcn_mfma_f32_32x32x16_bf16(kc1, q01, s0, 0, 0, 0);
        s1 = __builtin_amdgcn_mfma_f32_32x32x16_bf16(kc0, q10, s1, 0, 0, 0);
        s1 = __builtin_amdgcn_mfma_f32_32x32x16_bf16(kc1, q11, s1, 0, 0, 0);
        __builtin_amdgcn_s_setprio(0);

        bf16x8 p00, p01, p10, p11;
        softmax_tile(s0, ls0, p00, p01);
        softmax_tile(s1, ls1, p10, p11);

        // ---- PV: V fragments SHARED by both i-subtiles ----
        __builtin_amdgcn_s_setprio(1);
#define PVSTEP(CT, AA, AB) { \
        const bf16x8 v0_ = *(const bf16x8*)&Vt[cur][voff0[CT]]; \
        const bf16x8 v1_ = *(const bf16x8*)&Vt[cur][voff1[CT]]; \
        AA = __builtin_amdgcn_mfma_f32_32x32x16_bf16(v0_, p00, AA, 0, 0, 0); \
        AA = __builtin_amdgcn_mfma_f32_32x32x16_bf16(v1_, p01, AA, 0, 0, 0); \
        AB = __builtin_amdgcn_mfma_f32_32x32x16_bf16(v0_, p10, AB, 0, 0, 0); \
        AB = __builtin_amdgcn_mfma_f32_32x32x16_bf16(v1_, p11, AB, 0, 0, 0); }
        PVSTEP(0, a00, a10)
        PVSTEP(1, a01, a11)
        PVSTEP(2, a02, a12)
        PVSTEP(3, a03, a13)
#undef PVSTEP
        __builtin_amdgcn_s_setprio(0);

        __syncthreads();   // staged tile ready; cur buffer free for overwrite
        kc0 = kn0; kc1 = kn1;
    }

    // ---- merge lane-halves of lsums ----
    ls0 += __shfl_xor(ls0, 32);
    ls1 += __shfl_xor(ls1, 32);

    // ---- cross-js merge: lsums via lsx; accs via Vt (2 rounds) ----
    lsx[0][w * 64 + l] = ls0;
    lsx[1][w * 64 + l] = ls1;
    float* As = (float*)&Vt[0][0];     // 16384 floats
    const int base = (w >> 1) * 4096;  // same slot for js-partners

#define STORE_ACC(A, CT) { _Pragma("unroll") \
    for (int r = 0; r < 16; ++r) As[base + (CT) * 1024 + r * 64 + l] = A[r]; }
#define ADD_ACC(A, CT) { _Pragma("unroll") \
    for (int r = 0; r < 16; ++r) A[r] += As[base + (CT) * 1024 + r * 64 + l]; }

    __syncthreads();
    if (js == 1) { STORE_ACC(a00, 0) STORE_ACC(a01, 1) STORE_ACC(a02, 2) STORE_ACC(a03, 3) }
    __syncthreads();
    if (js == 0) { ADD_ACC(a00, 0) ADD_ACC(a01, 1) ADD_ACC(a02, 2) ADD_ACC(a03, 3) }
    __syncthreads();
    if (js == 1) { STORE_ACC(a10, 0) STORE_ACC(a11, 1) STORE_ACC(a12, 2) STORE_ACC(a13, 3) }
    __syncthreads();
    if (js == 0) { ADD_ACC(a10, 0) ADD_ACC(a11, 1) ADD_ACC(a12, 2) ADD_ACC(a13, 3) }
    __syncthreads();                   // all As reads done; Vt free again
#undef STORE_ACC
#undef ADD_ACC

    // ---- js0 waves: normalize + write bf16 ao-tile [n 0..127][c 0..255] ----
    // chunk q = c/8 (0..31); physical slot = q ^ (n & 7); addr = n*256 + slot*8 + 4*hi
    unsigned short* aoL = (unsigned short*)&Vt[0][0];   // 32768 shorts = 64 KB
    if (js == 0) {
        const float ra = 1.f / (ls0 + lsx[0][(w + 1) * 64 + l]);
        const float rb = 1.f / (ls1 + lsx[1][(w + 1) * 64 + l]);
        const int na  = ig * 64 + jl;
        const int nb2 = ig * 64 + 32 + jl;
#define EPIL(ACC, CT, NL, RL) { _Pragma("unroll") \
    for (int r4 = 0; r4 < 4; ++r4) { \
        const unsigned int d0 = (unsigned)f2b(ACC[r4*4+0] * (RL)) | \
                                ((unsigned)f2b(ACC[r4*4+1] * (RL)) << 16); \
        const unsigned int d1 = (unsigned)f2b(ACC[r4*4+2] * (RL)) | \
                                ((unsigned)f2b(ACC[r4*4+3] * (RL)) << 16); \
        const int q = cs * 16 + (CT) * 4 + r4; \
        *(uint2*)(aoL + (NL) * 256 + ((q ^ ((NL) & 7)) * 8) + 4 * hi) \
            = make_uint2(d0, d1); } }
        EPIL(a00, 0, na, ra)
        EPIL(a01, 1, na, ra)
        EPIL(a02, 2, na, ra)
        EPIL(a03, 3, na, ra)
        EPIL(a10, 0, nb2, rb)
        EPIL(a11, 1, nb2, rb)
        EPIL(a12, 2, nb2, rb)
        EPIL(a13, 3, nb2, rb)
#undef EPIL
    }
    __syncthreads();

    // ---- fused output projection: out = gamma*(W2 . ao + bo) + x ----
    // Wave w: c_out rows w*32..w*32+31, all 128 n (4 n-tiles).
    // A = W2 rows (L2), B = ao-tile (LDS, swizzled), k = 256.
    {
        const unsigned short* wrow = W2 + (size_t)(w * 32 + jl) * C_ + hi * 8;
        bf16x8 af[16];
        #pragma unroll
        for (int kk = 0; kk < 16; ++kk)
            af[kk] = *(const bf16x8*)(wrow + kk * 16);

        const float gm = gamma[0];
        #pragma unroll
        for (int nt = 0; nt < 4; ++nt) {
            f32x16 ac = (f32x16)0.f;
            #pragma unroll
            for (int kk = 0; kk < 16; ++kk) {
                const int q = kk * 2 + hi;
                const bf16x8 bf = *(const bf16x8*)
                    &aoL[(nt * 32 + jl) * 256 + ((q ^ (jl & 7)) * 8)];
                ac = __builtin_amdgcn_mfma_f32_32x32x16_bf16(af[kk], bf, ac, 0, 0, 0);
            }
            const int n = it * 128 + nt * 32 + jl;
            #pragma unroll
            for (int r4 = 0; r4 < 4; ++r4) {
                const float4 bi = *(const float4*)&bo[w * 32 + r4 * 8 + 4 * hi];
                #pragma unroll
                for (int e = 0; e < 4; ++e) {
                    const int crow = w * 32 + e + 8 * r4 + 4 * hi;
                    const size_t o = ((size_t)b * C_ + crow) * N_ + n;
                    out[o] = fmaf(gm, ac[r4*4+e] + ((const float*)&bi)[e], x[o]);
                }
            }
        }
    }
}

// ---------------------------------------------------------------------------
extern "C" void kernel_launch(void* const* d_in, const int* in_sizes, int n_in,
                              void* d_out, int out_size, void* d_ws, size_t ws_size,
                              hipStream_t stream)
{
    const float* x     = (const float*)d_in[0];
    const float* f     = (const float*)d_in[1];
    const float* wq    = (const float*)d_in[2];
    const float* bq    = (const float*)d_in[3];
    const float* wk    = (const float*)d_in[4];
    const float* bk    = (const float*)d_in[5];
    const float* wv    = (const float*)d_in[6];
    const float* bv    = (const float*)d_in[7];
    const float* wo    = (const float*)d_in[8];
    const float* bo    = (const float*)d_in[9];
    const float* gamma = (const float*)d_in[10];
    float* out = (float*)d_out;

    float* Bs1 = (float*)d_ws;
    unsigned short* W1 = (unsigned short*)(Bs1 + 320);
    unsigned short* W2 = W1 + 320 * C_;
    unsigned short* xT = W2 + 256 * C_;
    unsigned short* fT = xT + (size_t)B_ * N_ * C_;
    unsigned short* qT = fT + (size_t)B_ * N_ * C_;
    unsigned short* kT = qT + (size_t)B_ * N_ * CR_;
    unsigned short* vv = kT + (size_t)B_ * N_ * CR_;

    pack_kernel<<<dim3(576), 256, 0, stream>>>(wq, bq, wk, bk, wv, bv, wo, W1, W2, Bs1);
    convT_kernel<<<dim3(64, 4, 16), 256, 0, stream>>>(x, f, xT, fT);
    qkv_gemm<<<dim3(1280), 256, 0, stream>>>(xT, fT, W1, Bs1, qT, kT, vv);
    attn_kernel<<<dim3(256), 512, 0, stream>>>(qT, kT, vv, W2, bo, gamma, x, out);
}

// Round 13
// 144.638 us; speedup vs baseline: 1.1756x; 1.0013x over previous
//
#include <hip/hip_runtime.h>
#include <hip/hip_bf16.h>
#include <math.h>

#define B_  8
#define C_  256
#define CR_ 32
#define N_  4096

typedef __attribute__((ext_vector_type(8)))  short bf16x8;   // 8 bf16 = 4 VGPR
typedef __attribute__((ext_vector_type(16))) float f32x16;   // MFMA 32x32 acc
typedef __attribute__((ext_vector_type(4)))  int   int4v;

__device__ inline unsigned short f2b(float x) {
    __hip_bfloat16 h = __float2bfloat16(x);
    return __builtin_bit_cast(unsigned short, h);
}

// async 16B global->LDS (wave-uniform LDS base + lane*16; per-lane global src)
#define GLL16(gsrc, ldst) \
    __builtin_amdgcn_global_load_lds((const __attribute__((address_space(1))) void*)(gsrc), \
                                     (__attribute__((address_space(3))) void*)(ldst), 16, 0, 0)

// ---------------------------------------------------------------------------
// Kernel 0: pack weights to bf16.
//   W1[320][256]: rows 0-31 wq*log2e | 32-63 wk | 64-319 wv;  Bs1[320] fp32
//   W2[256][256]: wo
// ---------------------------------------------------------------------------
__global__ void pack_kernel(
    const float* __restrict__ wq, const float* __restrict__ bq,
    const float* __restrict__ wk, const float* __restrict__ bk,
    const float* __restrict__ wv, const float* __restrict__ bv,
    const float* __restrict__ wo,
    unsigned short* __restrict__ W1, unsigned short* __restrict__ W2,
    float* __restrict__ Bs1)
{
    const int r = blockIdx.x, t = threadIdx.x;
    const float L2E = 1.44269504088896340736f;
    if (r < 320) {
        float w;
        if (r < 32)      w = wq[r * C_ + t] * L2E;
        else if (r < 64) w = wk[(r - 32) * C_ + t];
        else             w = wv[(r - 64) * C_ + t];
        W1[r * C_ + t] = f2b(w);
        if (t == 0)
            Bs1[r] = (r < 32) ? bq[r] * L2E : ((r < 64) ? bk[r - 32] : bv[r - 64]);
    } else {
        W2[(r - 320) * C_ + t] = f2b(wo[(r - 320) * C_ + t]);
    }
}

// ---------------------------------------------------------------------------
// Kernel 1: transpose+convert  x,f fp32 [C,N] -> xT,fT bf16 [N,C].
// ---------------------------------------------------------------------------
__global__ __launch_bounds__(256) void convT_kernel(
    const float* __restrict__ x, const float* __restrict__ f,
    unsigned short* __restrict__ xT, unsigned short* __restrict__ fT)
{
    __shared__ float tile[64][65];
    const int t  = threadIdx.x;
    const int n0 = blockIdx.x * 64;
    const int c0 = blockIdx.y * 64;
    const int z  = blockIdx.z;
    const int b  = z >> 1;
    const float* src = (z & 1) ? f : x;
    unsigned short* dst = (z & 1) ? fT : xT;
    const size_t so = (size_t)b * C_ * N_;

    #pragma unroll
    for (int it = 0; it < 4; ++it) {
        const int cl = it * 16 + (t >> 4);
        *(float4*)&tile[cl][(t & 15) * 4] =
            *(const float4*)&src[so + (size_t)(c0 + cl) * N_ + n0 + (t & 15) * 4];
    }
    __syncthreads();

    const int nl = t >> 2;
    const int cg = (t & 3) * 16;
    unsigned short* drow = dst + ((size_t)b * N_ + n0 + nl) * C_ + c0 + cg;
    int4v w0, w1;
    #pragma unroll
    for (int e = 0; e < 4; ++e)
        w0[e] = (int)(((unsigned)f2b(tile[cg + 2*e][nl])) |
                      (((unsigned)f2b(tile[cg + 2*e + 1][nl])) << 16));
    #pragma unroll
    for (int e = 0; e < 4; ++e)
        w1[e] = (int)(((unsigned)f2b(tile[cg + 8 + 2*e][nl])) |
                      (((unsigned)f2b(tile[cg + 9 + 2*e][nl])) << 16));
    *(int4v*)(drow)     = w0;
    *(int4v*)(drow + 8) = w1;
}

// ---------------------------------------------------------------------------
// Shared MFMA GEMM mainloop (proven since R4).
// ---------------------------------------------------------------------------
__device__ __forceinline__ void gemm_mainloop(
    const unsigned short* __restrict__ Asrc,
    const unsigned short* __restrict__ Bsrc,
    unsigned short (*Ab)[32 * 32], unsigned short (*Bb)[256 * 32],
    int w, int l, f32x16& acc0, f32x16& acc1)
{
    const int jl = l & 31, hi = l >> 5;
    const int fj = (jl >> 1) & 3;

#define STAGE(KK, BUF) { \
    _Pragma("unroll") \
    for (int p = 0; p < 4; ++p) { \
        const int idx = p * 256 + w * 64 + l; \
        const int row = idx >> 2, slot = idx & 3; \
        GLL16(Bsrc + (size_t)row * 256 + (KK) * 32 + (slot ^ ((row >> 1) & 3)) * 8, \
              Bb[BUF] + (size_t)(p * 256 + w * 64) * 8); \
    } \
    if (w == 0) { \
        _Pragma("unroll") \
        for (int qq = 0; qq < 2; ++qq) { \
            const int idx = qq * 64 + l; \
            const int row = idx >> 2, slot = idx & 3; \
            GLL16(Asrc + (size_t)row * 256 + (KK) * 32 + (slot ^ ((row >> 1) & 3)) * 8, \
                  Ab[BUF] + (size_t)(qq * 64) * 8); \
        } \
    } }

    STAGE(0, 0)
    __syncthreads();

    for (int kk = 0; kk < 8; ++kk) {
        const int cur = kk & 1;
        if (kk < 7) STAGE(kk + 1, cur ^ 1)

        const unsigned short* Ac = Ab[cur];
        const unsigned short* Bc = Bb[cur];
        const bf16x8 af0 = *(const bf16x8*)&Ac[jl * 32 + ((hi ^ fj) * 8)];
        const bf16x8 af1 = *(const bf16x8*)&Ac[jl * 32 + (((2 + hi) ^ fj) * 8)];
        const int r0 = w * 64 + jl, r1 = w * 64 + 32 + jl;
        const bf16x8 bf00 = *(const bf16x8*)&Bc[r0 * 32 + ((hi ^ fj) * 8)];
        const bf16x8 bf01 = *(const bf16x8*)&Bc[r0 * 32 + (((2 + hi) ^ fj) * 8)];
        const bf16x8 bf10 = *(const bf16x8*)&Bc[r1 * 32 + ((hi ^ fj) * 8)];
        const bf16x8 bf11 = *(const bf16x8*)&Bc[r1 * 32 + (((2 + hi) ^ fj) * 8)];

        acc0 = __builtin_amdgcn_mfma_f32_32x32x16_bf16(af0, bf00, acc0, 0, 0, 0);
        acc0 = __builtin_amdgcn_mfma_f32_32x32x16_bf16(af1, bf01, acc0, 0, 0, 0);
        acc1 = __builtin_amdgcn_mfma_f32_32x32x16_bf16(af0, bf10, acc1, 0, 0, 0);
        acc1 = __builtin_amdgcn_mfma_f32_32x32x16_bf16(af1, bf11, acc1, 0, 0, 0);
        __syncthreads();
    }
#undef STAGE
}

// ---------------------------------------------------------------------------
// Kernel 2: QKV projection GEMM (proven since R4).
// ---------------------------------------------------------------------------
__global__ __launch_bounds__(256) void qkv_gemm(
    const unsigned short* __restrict__ xT, const unsigned short* __restrict__ fT,
    const unsigned short* __restrict__ W1, const float* __restrict__ Bs1,
    unsigned short* __restrict__ qT, unsigned short* __restrict__ kT,
    unsigned short* __restrict__ v)
{
    __shared__ __align__(16) unsigned short Ab[2][32 * 32];
    __shared__ __align__(16) unsigned short Bb[2][256 * 32];

    const int t = threadIdx.x;
    const int w = t >> 6, l = t & 63;
    const int jl = l & 31, hi = l >> 5;
    const int bid = blockIdx.x;
    const int b  = bid & 7;
    const int r_ = bid >> 3;
    const int mt = r_ % 10;
    const int nt = r_ / 10;

    const unsigned short* Asrc = W1 + (size_t)mt * 32 * C_;
    const unsigned short* Bsrc = ((mt == 0) ? xT : fT) + (size_t)b * N_ * C_
                               + (size_t)nt * 256 * C_;

    f32x16 acc0 = (f32x16)0.f, acc1 = (f32x16)0.f;
    gemm_mainloop(Asrc, Bsrc, Ab, Bb, w, l, acc0, acc1);

    const int m0 = mt * 32;
    const int nb = nt * 256 + w * 64;
    if (mt <= 1) {
        unsigned short* dst = ((mt == 0) ? qT : kT) + (size_t)b * N_ * CR_;
        #pragma unroll
        for (int ns = 0; ns < 2; ++ns) {
            const f32x16& A = ns ? acc1 : acc0;
            const int n = nb + ns * 32 + jl;
            #pragma unroll
            for (int r4 = 0; r4 < 4; ++r4) {
                const float4 bi = *(const float4*)&Bs1[m0 + r4 * 8 + 4 * hi];
                const unsigned int d0 = (unsigned)f2b(A[r4*4+0] + bi.x) |
                                        ((unsigned)f2b(A[r4*4+1] + bi.y) << 16);
                const unsigned int d1 = (unsigned)f2b(A[r4*4+2] + bi.z) |
                                        ((unsigned)f2b(A[r4*4+3] + bi.w) << 16);
                *(uint2*)(dst + (size_t)n * CR_ + r4 * 8 + 4 * hi) = make_uint2(d0, d1);
            }
        }
    } else {
        unsigned short* dst = v + (size_t)b * C_ * N_;
        #pragma unroll
        for (int ns = 0; ns < 2; ++ns) {
            const f32x16& A = ns ? acc1 : acc0;
            const int n = nb + ns * 32 + jl;
            #pragma unroll
            for (int r4 = 0; r4 < 4; ++r4) {
                const float4 bi = *(const float4*)&Bs1[m0 + r4 * 8 + 4 * hi];
                #pragma unroll
                for (int e = 0; e < 4; ++e) {
                    const int c = m0 - 64 + e + 8 * r4 + 4 * hi;
                    dst[(size_t)c * N_ + n] = f2b(A[r4*4+e] + ((const float*)&bi)[e]);
                }
            }
        }
    }
}

// ---------------------------------------------------------------------------
// Kernel 3: MFMA flash attention + FUSED output projection (proven R11).
// Grid 256 (1 block/CU), block 512 = 8 waves = 2 ig x 2 cs x 2 js.
// ---------------------------------------------------------------------------
__device__ inline void softmax_tile(const f32x16& s, float& lsum,
                                    bf16x8& pf0, bf16x8& pf1)
{
    float ps = 0.f;
    int wd[8];
    #pragma unroll
    for (int r = 0; r < 16; r += 2) {
        float e0 = __builtin_amdgcn_exp2f(s[r]);
        float e1 = __builtin_amdgcn_exp2f(s[r + 1]);
        ps += e0 + e1;
        int pk;
        asm("v_cvt_pk_bf16_f32 %0, %1, %2" : "=v"(pk) : "v"(e0), "v"(e1));
        wd[r >> 1] = pk;
    }
    lsum += ps;                       // per-lane partial; merged after the loop
    asm volatile("v_permlane32_swap_b32 %0, %1" : "+v"(wd[0]), "+v"(wd[2]));
    asm volatile("v_permlane32_swap_b32 %0, %1" : "+v"(wd[1]), "+v"(wd[3]));
    asm volatile("v_permlane32_swap_b32 %0, %1" : "+v"(wd[4]), "+v"(wd[6]));
    asm volatile("v_permlane32_swap_b32 %0, %1" : "+v"(wd[5]), "+v"(wd[7]));
    union { int4v i4; bf16x8 h8; } u0, u1;
    u0.i4 = (int4v){ wd[0], wd[1], wd[2], wd[3] };   // k = j0 .. j0+15
    u1.i4 = (int4v){ wd[4], wd[5], wd[6], wd[7] };   // k = j0+16 .. j0+31
    pf0 = u0.h8; pf1 = u1.h8;
}

__global__ __launch_bounds__(512) void attn_kernel(
    const unsigned short* __restrict__ qT, const unsigned short* __restrict__ kT,
    const unsigned short* __restrict__ v, const unsigned short* __restrict__ W2,
    const float* __restrict__ bo, const float* __restrict__ gamma,
    const float* __restrict__ x, float* __restrict__ out)
{
    __shared__ __align__(16) unsigned short Vt[2][256 * 64];  // 2 x 32 KB
    __shared__ float lsx[2][512];                             // 4 KB

    const int t  = threadIdx.x;
    const int w  = t >> 6;
    const int l  = t & 63;
    const int jl = l & 31;
    const int hi = l >> 5;
    const int js = w & 1;              // j-half of each 64-j tile
    const int ig = (w >> 1) & 1;       // 64-i subtile pair
    const int cs = w >> 2;             // 128-channel half

    const int bid = blockIdx.x;
    const int b   = bid & 7;           // XCD-local batch
    const int it  = bid >> 3;          // 0..31
    const int i0  = it * 128 + ig * 64;

    const unsigned short* qTb = qT + (size_t)b * N_ * CR_;
    const unsigned short* kTb = kT + (size_t)b * N_ * CR_;
    const unsigned short* vb  = v  + (size_t)b * C_ * N_;

    // Q fragments for both 32-i subtiles (B operand: col=i, k=d)
    const bf16x8 q00 = *(const bf16x8*)(qTb + (size_t)(i0 + jl) * CR_ + hi * 8);
    const bf16x8 q01 = *(const bf16x8*)(qTb + (size_t)(i0 + jl) * CR_ + 16 + hi * 8);
    const bf16x8 q10 = *(const bf16x8*)(qTb + (size_t)(i0 + 32 + jl) * CR_ + hi * 8);
    const bf16x8 q11 = *(const bf16x8*)(qTb + (size_t)(i0 + 32 + jl) * CR_ + 16 + hi * 8);

    // K rows for this wave's js-half: j = jt*64 + js*32 + jl
    const unsigned short* kln = kTb + (size_t)(js * 32 + jl) * CR_ + hi * 8;

    // ---- V staging (linear LDS dest + inverse-swizzled global src) ----
    const unsigned short* vsrc[4];
    int vdst[4];
    #pragma unroll
    for (int p = 0; p < 4; ++p) {
        const int idx = p * 512 + t;
        const int row = idx >> 3, slot = idx & 7;
        vsrc[p] = vb + (size_t)row * N_ + (slot ^ (row & 7)) * 8;
        vdst[p] = idx * 8;             // shorts (linear)
    }

    f32x16 a00 = (f32x16)0.f, a01 = (f32x16)0.f, a02 = (f32x16)0.f, a03 = (f32x16)0.f;
    f32x16 a10 = (f32x16)0.f, a11 = (f32x16)0.f, a12 = (f32x16)0.f, a13 = (f32x16)0.f;
    float ls0 = 0.f, ls1 = 0.f;

    // prologue: stage V tile 0; load K js-half 0 into registers
    #pragma unroll
    for (int p = 0; p < 4; ++p) GLL16(vsrc[p], &Vt[0][vdst[p]]);
    bf16x8 kc0 = *(const bf16x8*)(kln);
    bf16x8 kc1 = *(const bf16x8*)(kln + 16);
    __syncthreads();

    // V read offsets: row = c, chunk = js*4 + kk*2 + hi, slot = chunk^(row&7)
    int voff0[4], voff1[4];
    #pragma unroll
    for (int ct = 0; ct < 4; ++ct) {
        const int rv = cs * 128 + ct * 32 + jl;
        voff0[ct] = rv * 64 + (((js * 4 + hi)     ^ (rv & 7)) * 8);
        voff1[ct] = rv * 64 + (((js * 4 + 2 + hi) ^ (rv & 7)) * 8);
    }

    for (int jt = 0; jt < N_ / 64; ++jt) {
        const int cur = jt & 1;
        bf16x8 kn0 = kc0, kn1 = kc1;
        if (jt + 1 < N_ / 64) {        // prefetch next tile (V->LDS, K->regs)
            const size_t jn = (size_t)(jt + 1) * 64;
            #pragma unroll
            for (int p = 0; p < 4; ++p) GLL16(vsrc[p] + jn, &Vt[cur ^ 1][vdst[p]]);
            kn0 = *(const bf16x8*)(kln + jn * CR_);
            kn1 = *(const bf16x8*)(kln + jn * CR_ + 16);
        }

        // ---- S^T for both i-subtiles: A = K (row=j), B = Q (col=i) ----
        __builtin_amdgcn_s_setprio(1);
        f32x16 s0 = (f32x16)0.f, s1 = (f32x16)0.f;
        s0 = __builtin_amdgcn_mfma_f32_32x32x16_bf16(kc0, q00, s0, 0, 0, 0);
        s0 = __builtin_amdgcn_mfma_f32_32x32x16_bf16(kc1, q01, s0, 0, 0, 0);
        s1 = __builtin_amdgcn_mfma_f32_32x32x16_bf16(kc0, q10, s1, 0, 0, 0);
        s1 = __builtin_amdgcn_mfma_f32_32x32x16_bf16(kc1, q11, s1, 0, 0, 0);
        __builtin_amdgcn_s_setprio(0);

        bf16x8 p00, p01, p10, p11;
        softmax_tile(s0, ls0, p00, p01);
        softmax_tile(s1, ls1, p10, p11);

        // ---- PV: V fragments SHARED by both i-subtiles ----
        __builtin_amdgcn_s_setprio(1);
#define PVSTEP(CT, AA, AB) { \
        const bf16x8 v0_ = *(const bf16x8*)&Vt[cur][voff0[CT]]; \
        const bf16x8 v1_ = *(const bf16x8*)&Vt[cur][voff1[CT]]; \
        AA = __builtin_amdgcn_mfma_f32_32x32x16_bf16(v0_, p00, AA, 0, 0, 0); \
        AA = __builtin_amdgcn_mfma_f32_32x32x16_bf16(v1_, p01, AA, 0, 0, 0); \
        AB = __builtin_amdgcn_mfma_f32_32x32x16_bf16(v0_, p10, AB, 0, 0, 0); \
        AB = __builtin_amdgcn_mfma_f32_32x32x16_bf16(v1_, p11, AB, 0, 0, 0); }
        PVSTEP(0, a00, a10)
        PVSTEP(1, a01, a11)
        PVSTEP(2, a02, a12)
        PVSTEP(3, a03, a13)
#undef PVSTEP
        __builtin_amdgcn_s_setprio(0);

        __syncthreads();   // staged tile ready; cur buffer free for overwrite
        kc0 = kn0; kc1 = kn1;
    }

    // ---- merge lane-halves of lsums ----
    ls0 += __shfl_xor(ls0, 32);
    ls1 += __shfl_xor(ls1, 32);

    // ---- cross-js merge: lsums via lsx; accs via Vt (2 rounds) ----
    lsx[0][w * 64 + l] = ls0;
    lsx[1][w * 64 + l] = ls1;
    float* As = (float*)&Vt[0][0];     // 16384 floats
    const int base = (w >> 1) * 4096;  // same slot for js-partners

#define STORE_ACC(A, CT) { _Pragma("unroll") \
    for (int r = 0; r < 16; ++r) As[base + (CT) * 1024 + r * 64 + l] = A[r]; }
#define ADD_ACC(A, CT) { _Pragma("unroll") \
    for (int r = 0; r < 16; ++r) A[r] += As[base + (CT) * 1024 + r * 64 + l]; }

    __syncthreads();
    if (js == 1) { STORE_ACC(a00, 0) STORE_ACC(a01, 1) STORE_ACC(a02, 2) STORE_ACC(a03, 3) }
    __syncthreads();
    if (js == 0) { ADD_ACC(a00, 0) ADD_ACC(a01, 1) ADD_ACC(a02, 2) ADD_ACC(a03, 3) }
    __syncthreads();
    if (js == 1) { STORE_ACC(a10, 0) STORE_ACC(a11, 1) STORE_ACC(a12, 2) STORE_ACC(a13, 3) }
    __syncthreads();
    if (js == 0) { ADD_ACC(a10, 0) ADD_ACC(a11, 1) ADD_ACC(a12, 2) ADD_ACC(a13, 3) }
    __syncthreads();                   // all As reads done; Vt free again
#undef STORE_ACC
#undef ADD_ACC

    // ---- js0 waves: normalize + write bf16 ao-tile [n 0..127][c 0..255] ----
    // chunk q = c/8 (0..31); physical slot = q ^ (n & 7); addr = n*256 + slot*8 + 4*hi
    unsigned short* aoL = (unsigned short*)&Vt[0][0];   // 32768 shorts = 64 KB
    if (js == 0) {
        const float ra = 1.f / (ls0 + lsx[0][(w + 1) * 64 + l]);
        const float rb = 1.f / (ls1 + lsx[1][(w + 1) * 64 + l]);
        const int na  = ig * 64 + jl;
        const int nb2 = ig * 64 + 32 + jl;
#define EPIL(ACC, CT, NL, RL) { _Pragma("unroll") \
    for (int r4 = 0; r4 < 4; ++r4) { \
        const unsigned int d0 = (unsigned)f2b(ACC[r4*4+0] * (RL)) | \
                                ((unsigned)f2b(ACC[r4*4+1] * (RL)) << 16); \
        const unsigned int d1 = (unsigned)f2b(ACC[r4*4+2] * (RL)) | \
                                ((unsigned)f2b(ACC[r4*4+3] * (RL)) << 16); \
        const int q = cs * 16 + (CT) * 4 + r4; \
        *(uint2*)(aoL + (NL) * 256 + ((q ^ ((NL) & 7)) * 8) + 4 * hi) \
            = make_uint2(d0, d1); } }
        EPIL(a00, 0, na, ra)
        EPIL(a01, 1, na, ra)
        EPIL(a02, 2, na, ra)
        EPIL(a03, 3, na, ra)
        EPIL(a10, 0, nb2, rb)
        EPIL(a11, 1, nb2, rb)
        EPIL(a12, 2, nb2, rb)
        EPIL(a13, 3, nb2, rb)
#undef EPIL
    }
    __syncthreads();

    // ---- fused output projection: out = gamma*(W2 . ao + bo) + x ----
    // Wave w: c_out rows w*32..w*32+31, all 128 n (4 n-tiles).
    {
        const unsigned short* wrow = W2 + (size_t)(w * 32 + jl) * C_ + hi * 8;
        bf16x8 af[16];
        #pragma unroll
        for (int kk = 0; kk < 16; ++kk)
            af[kk] = *(const bf16x8*)(wrow + kk * 16);

        const float gm = gamma[0];
        #pragma unroll
        for (int nt = 0; nt < 4; ++nt) {
            f32x16 ac = (f32x16)0.f;
            #pragma unroll
            for (int kk = 0; kk < 16; ++kk) {
                const int q = kk * 2 + hi;
                const bf16x8 bf = *(const bf16x8*)
                    &aoL[(nt * 32 + jl) * 256 + ((q ^ (jl & 7)) * 8)];
                ac = __builtin_amdgcn_mfma_f32_32x32x16_bf16(af[kk], bf, ac, 0, 0, 0);
            }
            const int n = it * 128 + nt * 32 + jl;
            #pragma unroll
            for (int r4 = 0; r4 < 4; ++r4) {
                const float4 bi = *(const float4*)&bo[w * 32 + r4 * 8 + 4 * hi];
                #pragma unroll
                for (int e = 0; e < 4; ++e) {
                    const int crow = w * 32 + e + 8 * r4 + 4 * hi;
                    const size_t o = ((size_t)b * C_ + crow) * N_ + n;
                    out[o] = fmaf(gm, ac[r4*4+e] + ((const float*)&bi)[e], x[o]);
                }
            }
        }
    }
}

// ---------------------------------------------------------------------------
extern "C" void kernel_launch(void* const* d_in, const int* in_sizes, int n_in,
                              void* d_out, int out_size, void* d_ws, size_t ws_size,
                              hipStream_t stream)
{
    const float* x     = (const float*)d_in[0];
    const float* f     = (const float*)d_in[1];
    const float* wq    = (const float*)d_in[2];
    const float* bq    = (const float*)d_in[3];
    const float* wk    = (const float*)d_in[4];
    const float* bk    = (const float*)d_in[5];
    const float* wv    = (const float*)d_in[6];
    const float* bv    = (const float*)d_in[7];
    const float* wo    = (const float*)d_in[8];
    const float* bo    = (const float*)d_in[9];
    const float* gamma = (const float*)d_in[10];
    float* out = (float*)d_out;

    float* Bs1 = (float*)d_ws;
    unsigned short* W1 = (unsigned short*)(Bs1 + 320);
    unsigned short* W2 = W1 + 320 * C_;
    unsigned short* xT = W2 + 256 * C_;
    unsigned short* fT = xT + (size_t)B_ * N_ * C_;
    unsigned short* qT = fT + (size_t)B_ * N_ * C_;
    unsigned short* kT = qT + (size_t)B_ * N_ * CR_;
    unsigned short* vv = kT + (size_t)B_ * N_ * CR_;

    pack_kernel<<<dim3(576), 256, 0, stream>>>(wq, bq, wk, bk, wv, bv, wo, W1, W2, Bs1);
    convT_kernel<<<dim3(64, 4, 16), 256, 0, stream>>>(x, f, xT, fT);
    qkv_gemm<<<dim3(1280), 256, 0, stream>>>(xT, fT, W1, Bs1, qT, kT, vv);
    attn_kernel<<<dim3(256), 512, 0, stream>>>(qT, kT, vv, W2, bo, gamma, x, out);
}